// Round 11
// baseline (9762.585 us; speedup 1.0000x reference)
//
#include <hip/hip_runtime.h>
#include <hip/hip_bf16.h>
#include <hip/hip_cooperative_groups.h>

namespace cg = cooperative_groups;

#define SEQ 512
#define BATCH 128
#define INP 512
#define HID 1024
#define CLASSES 1000
#define NKX (INP / 32)        // 16
#define NKH (HID / 32)        // 32

#define NBLK 256
#define NTHR 256              // 4 waves; wave == gate
#define NGRP 4                // independent batch groups
#define GBLK 64               // blocks per group (h-col slices)
#define GROWS 32              // batch rows per group
#define NCOL 16               // h-cols per block
#define GRP_W ((size_t)512 * GROWS * HID)   // ring ushorts per group (32MB)

typedef float f32x4 __attribute__((ext_vector_type(4)));
typedef short bf16x8 __attribute__((ext_vector_type(8)));

__device__ __forceinline__ short f2bf16s(float f) {
    __hip_bfloat16 h = __float2bfloat16(f);
    return __builtin_bit_cast(short, h);
}
__device__ __forceinline__ float bf2f(unsigned short h) {
    union { unsigned u; float f; } v; v.u = ((unsigned)h) << 16;
    return v.f;
}
__device__ __forceinline__ float sigmoidf_(float x) {
    return 1.0f / (1.0f + __expf(-x));
}
__device__ __forceinline__ float tanhf_(float x) {
    x = fminf(fmaxf(x, -15.0f), 15.0f);
    float e = __expf(2.0f * x);
    return (e - 1.0f) / (e + 1.0f);
}
__device__ __forceinline__ int permbuf(int t) { return (t * 197) & 511; }

// ================= K1: fp32 -> bf16 convert (x, W_ih) =====================
#define XCH (SEQ * BATCH * INP / 8)
#define WCH (4 * HID * INP / 8)
__global__ __launch_bounds__(256)
void convert_bf16(const float* __restrict__ x, const float* __restrict__ W_ih,
                  unsigned short* __restrict__ xbf, unsigned short* __restrict__ Wbf) {
    const size_t total = XCH + WCH;
    for (size_t c = (size_t)blockIdx.x * blockDim.x + threadIdx.x; c < total;
         c += (size_t)gridDim.x * blockDim.x) {
        const float* src; unsigned short* dst;
        if (c < XCH) { src = x + c * 8;            dst = xbf + c * 8; }
        else         { src = W_ih + (c - XCH) * 8; dst = Wbf + (c - XCH) * 8; }
        const float4 a = *(const float4*)src;
        const float4 b = *(const float4*)(src + 4);
        bf16x8 v;
        v[0] = f2bf16s(a.x); v[1] = f2bf16s(a.y);
        v[2] = f2bf16s(a.z); v[3] = f2bf16s(a.w);
        v[4] = f2bf16s(b.x); v[5] = f2bf16s(b.y);
        v[6] = f2bf16s(b.z); v[7] = f2bf16s(b.w);
        *(bf16x8*)dst = v;
    }
}

// ================= K2: xproj -> bf16, grouped consumer order ==============
// Consumer lane reads ONE bf16x8 at ((((t*256+bid)*4+wave)*64+lane)*8:
// elems [0..3] = M-tile0 r0..3, [4..7] = M-tile1 r0..3.
// bid = group*64 + e (group = K2 wave w; e = hcol>>4); wave = gate.
__global__ __launch_bounds__(256)
void xproj_gemm(const unsigned short* __restrict__ xbf,
                const unsigned short* __restrict__ Wbf,
                unsigned short* __restrict__ xppb) {
    const int tid = threadIdx.x;
    const int w = tid >> 6;
    const int lane = tid & 63;
    const int ln15 = lane & 15;
    const int lgrp = lane >> 4;
    const int k8 = lgrp * 8;
    const int bx = blockIdx.x;                    // timestep t
    const int m0 = bx * 128 + w * 32 + ln15;
    const int n0 = blockIdx.y * 128 + ln15;

    f32x4 acc[2][8];
    #pragma unroll
    for (int i = 0; i < 2; i++)
        #pragma unroll
        for (int j = 0; j < 8; j++) acc[i][j] = (f32x4){0.f, 0.f, 0.f, 0.f};

    #pragma unroll 4
    for (int kt = 0; kt < INP / 32; kt++) {
        const int k = kt * 32 + k8;
        bf16x8 a0 = *(const bf16x8*)(xbf + (size_t)m0 * INP + k);
        bf16x8 a1 = *(const bf16x8*)(xbf + (size_t)(m0 + 16) * INP + k);
        #pragma unroll
        for (int nt = 0; nt < 8; nt++) {
            bf16x8 b = *(const bf16x8*)(Wbf + (size_t)(n0 + nt * 16) * INP + k);
            acc[0][nt] = __builtin_amdgcn_mfma_f32_16x16x32_bf16(a0, b, acc[0][nt], 0, 0, 0);
            acc[1][nt] = __builtin_amdgcn_mfma_f32_16x16x32_bf16(a1, b, acc[1][nt], 0, 0, 0);
        }
    }
    // C/D: m_in_tile = lgrp*4 + r, n = ln15; K2 lane index == consumer lane.
    #pragma unroll
    for (int nt = 0; nt < 8; nt++) {
        const int nG   = blockIdx.y * 128 + nt * 16 + ln15;
        const int gate = nG >> 10;
        const int colh = nG & 1023;
        const int bidT = w * GBLK + (colh >> 4);
        size_t base = ((((size_t)bx * NBLK + bidT) * 4 + gate) * 64
                       + (size_t)lane) * 8;
        bf16x8 v;
        #pragma unroll
        for (int r = 0; r < 4; r++) {
            v[r]     = f2bf16s(acc[0][nt][r]);
            v[4 + r] = f2bf16s(acc[1][nt][r]);
        }
        *(bf16x8*)(xppb + base) = v;
    }
}

// ================= K3: grouped recurrent kernel ===========================
__global__ __launch_bounds__(NTHR)
void lstm_groups(const float* __restrict__ W_hh,
                 const float* __restrict__ b_ih,
                 const float* __restrict__ b_hh,
                 const float* __restrict__ W_fc,
                 const float* __restrict__ b_fc,
                 float* __restrict__ out,
                 const unsigned short* __restrict__ xppb,
                 const unsigned short* __restrict__ xbf,
                 const unsigned short* __restrict__ Wbf,
                 unsigned short* __restrict__ ring,
                 unsigned short* __restrict__ h0,
                 unsigned short* __restrict__ h1,
                 int use_xp, int use_ring,
                 unsigned* __restrict__ flags)
{
    __shared__ short W_sw[4 * 32 * 64 * 8];    // 131072 B, [wave][kt][lane][8]
    __shared__ float gw[64][33];               // [gate*16+c][m], 8448 B

    const int tid = threadIdx.x;
    const int bid = blockIdx.x;
    const int g   = bid >> 6;                  // group 0..3
    const int e   = bid & 63;                  // h-col slice in group

    const int wave = tid >> 6;                 // == gate
    const int lane = tid & 63;
    const int ln15 = lane & 15;
    const int lgrp = lane >> 4;

    // ---- one-time init: W_hh slice -> LDS, fragment order ----
    for (int f = tid; f < 4 * 32 * 64; f += NTHR) {
        const int ln = f & 63;
        const int kt = (f >> 6) & 31;
        const int w  = f >> 11;
        const int rg = w * HID + e * NCOL + (ln & 15);
        const int k  = kt * 32 + (ln >> 4) * 8;
        short tmp[8];
        #pragma unroll
        for (int j = 0; j < 8; j++)
            tmp[j] = f2bf16s(W_hh[(size_t)rg * HID + k + j]);
        *(bf16x8*)&W_sw[(size_t)f * 8] = *(bf16x8*)tmp;
    }
    {   // zero h buffers: ring buf0 of each group (write-through) + h0 dbuf
        const unsigned gt = (unsigned)bid * NTHR + tid;     // 0..65535
        if (use_ring) {
            const unsigned grp = gt >> 14, off = gt & 16383;
            __hip_atomic_store((unsigned*)ring + (size_t)grp * (GRP_W / 2) + off,
                               0u, __ATOMIC_RELAXED, __HIP_MEMORY_SCOPE_AGENT);
        }
        ((unsigned*)h0)[gt] = 0u;
    }
    if (bid == 0) {
        for (int i = tid; i < 4096; i += NTHR) flags[i] = 0u;
    }

    // cell update: 2 cells/thread (cm row, cp col pair)
    const int cm = tid >> 3;                   // 0..31
    const int cp = (tid & 7) * 2;              // 0,2,..,14
    float c_r[2] = {0.f, 0.f};
    float bias_r[2][4];
    #pragma unroll
    for (int jj = 0; jj < 2; jj++)
        #pragma unroll
        for (int g4 = 0; g4 < 4; g4++) {
            const int r = g4 * HID + e * NCOL + cp + jj;
            bias_r[jj][g4] = b_ih[r] + b_hh[r];
        }

    __syncthreads();
    cg::this_grid().sync();   // publish init; invalidates L1/L2 everywhere

    const bf16x8* Wb = (const bf16x8*)W_sw + (size_t)wave * 32 * 64 + lane;
    unsigned short* const ringG = ring + (size_t)g * GRP_W;
    unsigned* const flagG = flags + g * 1024;

    for (int t = 0; t < SEQ; t++) {
        const unsigned short* hb;
        unsigned short* hn;
        if (use_ring) {
            hb = ringG + (size_t)permbuf(t) * (GROWS * HID);
            hn = ringG + (size_t)permbuf(t + 1) * (GROWS * HID);
        } else {
            hb = ((t & 1) ? h1 : h0) + (size_t)g * GROWS * HID;
            hn = ((t & 1) ? h0 : h1) + (size_t)g * GROWS * HID;
        }

        f32x4 acc0 = {0.f,0.f,0.f,0.f};
        f32x4 acc1 = {0.f,0.f,0.f,0.f};
        bf16x8 xv = {0,0,0,0,0,0,0,0};

        // ---- h-independent part BEFORE the wait ----
        if (use_xp) {
            xv = *(const bf16x8*)(xppb +
                  ((((size_t)t * NBLK + bid) * 4 + wave) * 64 + (size_t)lane) * 8);
        } else {
            // fallback: x-GEMM with Wbf fragments from global (L2-resident)
            const unsigned short* xr0 =
                xbf + ((size_t)t * BATCH + g * GROWS + ln15) * INP + lgrp * 8;
            const unsigned short* xr1 = xr0 + 16 * INP;
            const unsigned short* wbr =
                Wbf + (size_t)(wave * HID + e * NCOL + ln15) * INP + lgrp * 8;
            #pragma unroll
            for (int kt = 0; kt < NKX; kt++) {
                bf16x8 a0 = *(const bf16x8*)(xr0 + kt * 32);
                bf16x8 a1 = *(const bf16x8*)(xr1 + kt * 32);
                bf16x8 b  = *(const bf16x8*)(wbr + kt * 32);
                acc0 = __builtin_amdgcn_mfma_f32_16x16x32_bf16(a0, b, acc0, 0, 0, 0);
                acc1 = __builtin_amdgcn_mfma_f32_16x16x32_bf16(a1, b, acc1, 0, 0, 0);
            }
        }

        // ---- wait for this group's 64 producers ----
        {
            const unsigned* fp = &flagG[lane * 16];
            for (;;) {
                unsigned f = __hip_atomic_load(fp, __ATOMIC_RELAXED,
                                               __HIP_MEMORY_SCOPE_AGENT);
                if (__all(f >= (unsigned)t)) break;
                __builtin_amdgcn_s_sleep(1);
            }
            if (!use_ring)
                __builtin_amdgcn_fence(__ATOMIC_ACQUIRE, "agent");
            asm volatile("" ::: "memory");
        }

        // ---- h-GEMM: M=32, N=16 (this wave's gate slice), K=1024 ----
        {
            const unsigned short* hr0 = hb + (size_t)ln15 * HID + lgrp * 8;
            const unsigned short* hr1 = hr0 + 16 * HID;
            #pragma unroll
            for (int kt = 0; kt < NKH; kt++) {
                bf16x8 a0 = *(const bf16x8*)(hr0 + kt * 32);
                bf16x8 a1 = *(const bf16x8*)(hr1 + kt * 32);
                bf16x8 b  = Wb[kt * 64];
                acc0 = __builtin_amdgcn_mfma_f32_16x16x32_bf16(a0, b, acc0, 0, 0, 0);
                acc1 = __builtin_amdgcn_mfma_f32_16x16x32_bf16(a1, b, acc1, 0, 0, 0);
            }
        }
        if (use_xp) {
            #pragma unroll
            for (int r = 0; r < 4; r++) {
                acc0[r] += bf2f((unsigned short)xv[r]);
                acc1[r] += bf2f((unsigned short)xv[4 + r]);
            }
        }

        // ---- transpose to LDS (C/D: m = lgrp*4 + r, n = ln15) ----
        {
            const int nr = wave * 16 + ln15;
            #pragma unroll
            for (int r = 0; r < 4; r++) {
                gw[nr][lgrp * 4 + r]      = acc0[r];
                gw[nr][16 + lgrp * 4 + r] = acc1[r];
            }
        }
        __syncthreads();

        // ---- cell update: 2 cells/thread + one 4B write-through store ----
        {
            unsigned pack = 0;
            #pragma unroll
            for (int jj = 0; jj < 2; jj++) {
                const int col = cp + jj;
                float ig = gw[col][cm]      + bias_r[jj][0];
                float fg = gw[16 + col][cm] + bias_r[jj][1];
                float gg = gw[32 + col][cm] + bias_r[jj][2];
                float og = gw[48 + col][cm] + bias_r[jj][3];
                ig = sigmoidf_(ig); fg = sigmoidf_(fg);
                gg = tanhf_(gg);    og = sigmoidf_(og);
                float cc = fg * c_r[jj] + ig * gg;
                c_r[jj] = cc;
                float h = og * tanhf_(cc);
                pack |= ((unsigned)(unsigned short)f2bf16s(h)) << (16 * jj);
            }
            __hip_atomic_store((unsigned*)(hn + (size_t)cm * HID + e * NCOL + cp),
                               pack, __ATOMIC_RELAXED, __HIP_MEMORY_SCOPE_AGENT);
        }
        asm volatile("s_waitcnt vmcnt(0)" ::: "memory");   // stores acked at L3
        __syncthreads();                                    // all threads acked
        if (tid == 0)
            __hip_atomic_store(&flagG[e * 16], (unsigned)(t + 1),
                               __ATOMIC_RELAXED, __HIP_MEMORY_SCOPE_AGENT);
    }

    cg::this_grid().sync();   // full release/acquire (inv) before epilogue

    // ---- FC epilogue: h_last at ring buf permbuf(512)=0 (or h0 dbuf) ----
    for (unsigned idx = (unsigned)bid * NTHR + tid; idx < BATCH * CLASSES;
         idx += (unsigned)NBLK * NTHR) {
        const int b   = idx / CLASSES;
        const int cls = idx % CLASSES;
        const unsigned short* hrow = use_ring
            ? ring + (size_t)(b >> 5) * GRP_W + (size_t)(b & 31) * HID
            : h0 + (size_t)b * HID;
        const float* wrow = W_fc + (size_t)cls * HID;
        float acc = 0.f;
        #pragma unroll 4
        for (int k = 0; k < HID; k += 8) {
            bf16x8 hv = *(const bf16x8*)(hrow + k);
            float4 w0 = *(const float4*)(wrow + k);
            float4 w1 = *(const float4*)(wrow + k + 4);
            float s = 0.f;
            s += bf2f((unsigned short)hv[0]) * w0.x;
            s += bf2f((unsigned short)hv[1]) * w0.y;
            s += bf2f((unsigned short)hv[2]) * w0.z;
            s += bf2f((unsigned short)hv[3]) * w0.w;
            s += bf2f((unsigned short)hv[4]) * w1.x;
            s += bf2f((unsigned short)hv[5]) * w1.y;
            s += bf2f((unsigned short)hv[6]) * w1.z;
            s += bf2f((unsigned short)hv[7]) * w1.w;
            acc += s;
        }
        out[idx] = acc + b_fc[cls];
    }
}

extern "C" void kernel_launch(void* const* d_in, const int* in_sizes, int n_in,
                              void* d_out, int out_size, void* d_ws, size_t ws_size,
                              hipStream_t stream) {
    const float* x    = (const float*)d_in[0];
    const float* W_ih = (const float*)d_in[1];
    const float* W_hh = (const float*)d_in[2];
    const float* b_ih = (const float*)d_in[3];
    const float* b_hh = (const float*)d_in[4];
    const float* W_fc = (const float*)d_in[5];
    const float* b_fc = (const float*)d_in[6];
    float* out = (float*)d_out;

    // ws layout: h0 | h1 | xbf(64MB) | Wbf(4MB) | xppb(512MB bf16) | ring(128MB)
    const size_t OFF_H1   = (size_t)BATCH * HID * 2;                // 256 KB
    const size_t OFF_XBF  = 2 * OFF_H1;                             // 512 KB
    const size_t XBF_B    = (size_t)SEQ * BATCH * INP * 2;          // 64 MB
    const size_t OFF_WBF  = OFF_XBF + XBF_B;
    const size_t WBF_B    = (size_t)4 * HID * INP * 2;              // 4 MB
    const size_t OFF_XPPB = OFF_WBF + WBF_B;
    const size_t XPPB_B   = (size_t)SEQ * BATCH * 4 * HID * 2;      // 512 MB
    const size_t OFF_RING = OFF_XPPB + XPPB_B;
    const size_t RING_B   = (size_t)NGRP * GRP_W * 2;               // 128 MB

    unsigned short* h0   = (unsigned short*)d_ws;
    unsigned short* h1   = (unsigned short*)((char*)d_ws + OFF_H1);
    unsigned short* xbf  = (unsigned short*)((char*)d_ws + OFF_XBF);
    unsigned short* Wbf  = (unsigned short*)((char*)d_ws + OFF_WBF);
    unsigned short* xppb = (unsigned short*)((char*)d_ws + OFF_XPPB);
    unsigned short* ring = (unsigned short*)((char*)d_ws + OFF_RING);

    int use_xp   = (ws_size >= OFF_XPPB + XPPB_B) ? 1 : 0;
    int use_ring = (ws_size >= OFF_RING + RING_B) ? 1 : 0;

    convert_bf16<<<dim3(2048), dim3(256), 0, stream>>>(x, W_ih, xbf, Wbf);
    if (use_xp) {
        xproj_gemm<<<dim3(512, 32), dim3(256), 0, stream>>>(xbf, Wbf, xppb);
    }

    unsigned* flags = (unsigned*)d_out;   // 16KB of d_out; overwritten by FC

    void* args[] = {&W_hh, &b_ih, &b_hh, &W_fc, &b_fc, &out,
                    &xppb, &xbf, &Wbf, &ring, &h0, &h1,
                    &use_xp, &use_ring, &flags};
    hipLaunchCooperativeKernel((void*)lstm_groups, dim3(NBLK), dim3(NTHR),
                               args, 0, stream);
}

// Round 12
// 6990.578 us; speedup vs baseline: 1.3965x; 1.3965x over previous
//
#include <hip/hip_runtime.h>
#include <hip/hip_bf16.h>
#include <hip/hip_cooperative_groups.h>

namespace cg = cooperative_groups;

#define SEQ 512
#define BATCH 128
#define INP 512
#define HID 1024
#define CLASSES 1000
#define KTOT (INP + HID)      // 1536
#define NKT (KTOT / 32)       // 48
#define NKX (INP / 32)        // 16
#define NKH (HID / 32)        // 32

#define NBLK 128              // worker blocks
#define HBLK 128              // heater blocks
#define GRID (NBLK + HBLK)    // 256
#define NTHR 512              // 8 waves, M=16 per wave (R6-proven geometry)
#define BJ 8                  // h-columns per worker block
#define G4H (4 * HID)

typedef float f32x4 __attribute__((ext_vector_type(4)));
typedef short bf16x8 __attribute__((ext_vector_type(8)));

__device__ __forceinline__ short f2bf16s(float f) {
    __hip_bfloat16 h = __float2bfloat16(f);
    return __builtin_bit_cast(short, h);
}
__device__ __forceinline__ float sigmoidf_(float x) {
    return 1.0f / (1.0f + __expf(-x));
}
__device__ __forceinline__ float tanhf_(float x) {
    x = fminf(fmaxf(x, -15.0f), 15.0f);
    float e = __expf(2.0f * x);
    return (e - 1.0f) / (e + 1.0f);
}

// ================= K1: fp32 -> bf16 convert (x, optionally W_ih) =========
#define XCH (SEQ * BATCH * INP / 8)
#define WCH (4 * HID * INP / 8)
__global__ __launch_bounds__(256)
void convert_bf16(const float* __restrict__ x, const float* __restrict__ W_ih,
                  unsigned short* __restrict__ xbf, unsigned short* __restrict__ Wbf,
                  int do_w) {
    const size_t total = XCH + (do_w ? WCH : 0);
    for (size_t c = (size_t)blockIdx.x * blockDim.x + threadIdx.x; c < total;
         c += (size_t)gridDim.x * blockDim.x) {
        const float* src; unsigned short* dst;
        if (c < XCH) { src = x + c * 8;            dst = xbf + c * 8; }
        else         { src = W_ih + (c - XCH) * 8; dst = Wbf + (c - XCH) * 8; }
        const float4 a = *(const float4*)src;
        const float4 b = *(const float4*)(src + 4);
        bf16x8 v;
        v[0] = f2bf16s(a.x); v[1] = f2bf16s(a.y);
        v[2] = f2bf16s(a.z); v[3] = f2bf16s(a.w);
        v[4] = f2bf16s(b.x); v[5] = f2bf16s(b.y);
        v[6] = f2bf16s(b.z); v[7] = f2bf16s(b.w);
        *(bf16x8*)dst = v;
    }
}

// ================= K2: xproj -> CONSUMER-ORDER layout (fp32, R6) ==========
// xpp dword addr: ((t*128 + bid)*8 + wave)*512 + (lgrp*16 + l)*8 + half*4 + r
__global__ __launch_bounds__(256)
void xproj_gemm(const unsigned short* __restrict__ xbf,
                const unsigned short* __restrict__ Wbf,
                float* __restrict__ xpp) {
    const int tid = threadIdx.x;
    const int w = tid >> 6;
    const int lane = tid & 63;
    const int ln15 = lane & 15;
    const int lgrp = lane >> 4;
    const int k8 = lgrp * 8;
    const int m0 = blockIdx.x * 128 + w * 32 + ln15;   // t = blockIdx.x
    const int n0 = blockIdx.y * 128 + ln15;

    f32x4 acc[2][8];
    #pragma unroll
    for (int i = 0; i < 2; i++)
        #pragma unroll
        for (int j = 0; j < 8; j++) acc[i][j] = (f32x4){0.f, 0.f, 0.f, 0.f};

    #pragma unroll 4
    for (int kt = 0; kt < INP / 32; kt++) {
        const int k = kt * 32 + k8;
        bf16x8 a0 = *(const bf16x8*)(xbf + (size_t)m0 * INP + k);
        bf16x8 a1 = *(const bf16x8*)(xbf + (size_t)(m0 + 16) * INP + k);
        #pragma unroll
        for (int nt = 0; nt < 8; nt++) {
            bf16x8 b = *(const bf16x8*)(Wbf + (size_t)(n0 + nt * 16) * INP + k);
            acc[0][nt] = __builtin_amdgcn_mfma_f32_16x16x32_bf16(a0, b, acc[0][nt], 0, 0, 0);
            acc[1][nt] = __builtin_amdgcn_mfma_f32_16x16x32_bf16(a1, b, acc[1][nt], 0, 0, 0);
        }
    }
    #pragma unroll
    for (int nt = 0; nt < 8; nt++) {
        const int n = blockIdx.y * 128 + nt * 16 + ln15;
        const int bid3 = (n & 1023) >> 3;
        const int half = n >> 11;
        const int l3 = (n & 7) | (((n >> 10) & 1) << 3);
        #pragma unroll
        for (int mi = 0; mi < 2; mi++) {
            const int w3 = w * 2 + mi;
            size_t base = (((size_t)blockIdx.x * 128 + bid3) * 8 + w3) * 512
                        + (size_t)(lgrp * 16 + l3) * 8 + half * 4;
            *(float4*)(xpp + base) = *(float4*)&acc[mi][nt];
        }
    }
}

// ================= K3: recurrent loop + heater blocks =====================
__device__ __forceinline__ void bar_signal(unsigned* flags, int bid, unsigned val) {
    __hip_atomic_store(&flags[bid], val, __ATOMIC_RELAXED,
                       __HIP_MEMORY_SCOPE_AGENT);
}
// wave0 polls all 128 worker flags; PURE SPIN (no s_sleep); acquire-inv after
__device__ __forceinline__ void bar_wait_all(const unsigned* flags, int lane,
                                             unsigned want) {
    const unsigned* p0 = &flags[lane];
    const unsigned* p1 = &flags[64 + lane];
    for (;;) {
        unsigned f0 = __hip_atomic_load(p0, __ATOMIC_RELAXED,
                                        __HIP_MEMORY_SCOPE_AGENT);
        unsigned f1 = __hip_atomic_load(p1, __ATOMIC_RELAXED,
                                        __HIP_MEMORY_SCOPE_AGENT);
        if (__all((f0 >= want) && (f1 >= want))) break;
    }
    __builtin_amdgcn_fence(__ATOMIC_ACQUIRE, "agent");  // inv L1/L2 -> fresh h
}

__global__ __launch_bounds__(NTHR)
void lstm_fused(const float* __restrict__ x,
                const float* __restrict__ W_ih,
                const float* __restrict__ W_hh,
                const float* __restrict__ b_ih,
                const float* __restrict__ b_hh,
                const float* __restrict__ W_fc,
                const float* __restrict__ b_fc,
                float* __restrict__ out,
                unsigned short* __restrict__ h0,
                unsigned short* __restrict__ h1,
                unsigned short* __restrict__ xbf,
                const float* __restrict__ xpp,
                int use_xbf, int use_xp,
                unsigned* __restrict__ flags)
{
    __shared__ short W_sw[2 * NKT * 64 * 8];   // 98304 B, MFMA-fragment order
    __shared__ float gw[8][16][33];            // per-wave gate transpose
    __shared__ volatile unsigned hdone;        // heater stop signal (LDS)

    const int tid = threadIdx.x;
    const int bid = blockIdx.x;
    const bool worker = (bid < NBLK);
    const int j0 = bid * BJ;

    const int wave = tid >> 6;
    const int lane = tid & 63;
    const int ln15 = lane & 15;
    const int lgrp = lane >> 4;
    const int arow = wave * 16 + ln15;
    const int k8 = lgrp * 8;

    // cell-update assignment (worker): 128 cells/wave, 2 per thread
    const int crow = lane >> 2;
    const int cp   = (lane & 3) * 2;
    const int bg   = wave * 16 + crow;
    float c_r[2] = {0.f, 0.f};
    float bias_r[2][4];

    if (worker) {
        // ---------------- one-time init ----------------
        for (int f = tid; f < 2 * NKT * 64; f += NTHR) {
            const int ln = f & 63;
            const int kt = (f >> 6) % NKT;
            const int nt = f / (NKT * 64);
            const int n = nt * 16 + (ln & 15);
            const int r = (n >> 3) * HID + j0 + (n & 7);
            const int kbase = kt * 32 + (ln >> 4) * 8;
            short tmp[8];
            #pragma unroll
            for (int j = 0; j < 8; j++) {
                const int k = kbase + j;
                float w = (k < INP) ? W_ih[(size_t)r * INP + k]
                                    : W_hh[(size_t)r * HID + (k - INP)];
                tmp[j] = f2bf16s(w);
            }
            *(bf16x8*)&W_sw[(size_t)f * 8] = *(bf16x8*)tmp;
        }
        {   // zero h0: 65536 dwords over the 65536 worker threads
            const unsigned g = (unsigned)bid * NTHR + tid;
            ((unsigned*)h0)[g] = 0u;
        }
        if (bid == 0) {
            for (int i = tid; i < NBLK; i += NTHR) flags[i] = 0u;
        }
        #pragma unroll
        for (int jj = 0; jj < 2; jj++)
            #pragma unroll
            for (int g = 0; g < 4; g++) {
                const int r = g * HID + j0 + cp + jj;
                bias_r[jj][g] = b_ih[r] + b_hh[r];
            }
    }
    if (tid == 0) hdone = 0u;
    __syncthreads();
    cg::this_grid().sync();   // publish h0/flags/xbf/xpp grid-wide

    if (worker) {
        const bf16x8* Wl = (const bf16x8*)W_sw + lane;

        for (int t = 0; t < SEQ; t++) {
            const unsigned short* __restrict__ hp = (t & 1) ? h1 : h0;
            unsigned short* __restrict__ hcur     = (t & 1) ? h0 : h1;

            f32x4 acc00, acc01;

            // ---- h-independent part BEFORE the wait ----
            if (use_xp) {
                const float* xrow = xpp + (((size_t)t * NBLK + bid) * 8 + wave) * 512
                                        + (size_t)(lgrp * 16 + ln15) * 8;
                const float4 xv0 = *(const float4*)xrow;
                const float4 xv1 = *(const float4*)(xrow + 4);
                acc00[0] = xv0.x; acc00[1] = xv0.y; acc00[2] = xv0.z; acc00[3] = xv0.w;
                acc01[0] = xv1.x; acc01[1] = xv1.y; acc01[2] = xv1.z; acc01[3] = xv1.w;
            } else {
                acc00 = (f32x4){0.f,0.f,0.f,0.f};
                acc01 = (f32x4){0.f,0.f,0.f,0.f};
                if (use_xbf) {
                    const unsigned short* xr =
                        xbf + (size_t)t * (BATCH * INP) + (size_t)arow * INP + k8;
                    #pragma unroll
                    for (int kt = 0; kt < NKX; kt++) {
                        bf16x8 a  = *(const bf16x8*)(xr + kt * 32);
                        bf16x8 b0 = Wl[kt * 64];
                        bf16x8 b1 = Wl[(NKT + kt) * 64];
                        acc00 = __builtin_amdgcn_mfma_f32_16x16x32_bf16(a, b0, acc00, 0, 0, 0);
                        acc01 = __builtin_amdgcn_mfma_f32_16x16x32_bf16(a, b1, acc01, 0, 0, 0);
                    }
                } else {
                    const float* xr =
                        x + (size_t)t * (BATCH * INP) + (size_t)arow * INP + k8;
                    #pragma unroll
                    for (int kt = 0; kt < NKX; kt++) {
                        const float4 xa = *(const float4*)(xr + kt * 32);
                        const float4 xb = *(const float4*)(xr + kt * 32 + 4);
                        bf16x8 a;
                        a[0]=f2bf16s(xa.x); a[1]=f2bf16s(xa.y); a[2]=f2bf16s(xa.z); a[3]=f2bf16s(xa.w);
                        a[4]=f2bf16s(xb.x); a[5]=f2bf16s(xb.y); a[6]=f2bf16s(xb.z); a[7]=f2bf16s(xb.w);
                        bf16x8 b0 = Wl[kt * 64];
                        bf16x8 b1 = Wl[(NKT + kt) * 64];
                        acc00 = __builtin_amdgcn_mfma_f32_16x16x32_bf16(a, b0, acc00, 0, 0, 0);
                        acc01 = __builtin_amdgcn_mfma_f32_16x16x32_bf16(a, b1, acc01, 0, 0, 0);
                    }
                }
            }

            // ---- wait for h_t ----
            if (tid < 64) bar_wait_all(flags, lane, (unsigned)t);
            __syncthreads();

            // ---- h-part: pipelined b128 loads (post-inv, L2 refills) ----
            {
                const unsigned short* hr = hp + (size_t)arow * HID + k8;
                #pragma unroll
                for (int kt = 0; kt < NKH; kt++) {
                    bf16x8 a  = *(const bf16x8*)(hr + kt * 32);
                    bf16x8 b0 = Wl[(NKX + kt) * 64];
                    bf16x8 b1 = Wl[(NKT + NKX + kt) * 64];
                    acc00 = __builtin_amdgcn_mfma_f32_16x16x32_bf16(a, b0, acc00, 0, 0, 0);
                    acc01 = __builtin_amdgcn_mfma_f32_16x16x32_bf16(a, b1, acc01, 0, 0, 0);
                }
            }

            // ---- wave-private transpose ----
            {
                const int r0 = lgrp * 4;
                #pragma unroll
                for (int r = 0; r < 4; r++) {
                    gw[wave][r0 + r][ln15]      = acc00[r];
                    gw[wave][r0 + r][16 + ln15] = acc01[r];
                }
            }

            // ---- cell update: 2 cells/thread ----
            {
                unsigned pack = 0;
                #pragma unroll
                for (int jj = 0; jj < 2; jj++) {
                    const int dj = cp + jj;
                    float ig = gw[wave][crow][dj]      + bias_r[jj][0];
                    float fg = gw[wave][crow][8 + dj]  + bias_r[jj][1];
                    float gg = gw[wave][crow][16 + dj] + bias_r[jj][2];
                    float og = gw[wave][crow][24 + dj] + bias_r[jj][3];
                    ig = sigmoidf_(ig); fg = sigmoidf_(fg);
                    gg = tanhf_(gg);    og = sigmoidf_(og);
                    float cc = fg * c_r[jj] + ig * gg;
                    c_r[jj] = cc;
                    float h = og * tanhf_(cc);
                    pack |= ((unsigned)(unsigned short)f2bf16s(h)) << (16 * jj);
                }
                __hip_atomic_store((unsigned*)(hcur + (size_t)bg * HID + j0 + cp),
                                   pack, __ATOMIC_RELAXED, __HIP_MEMORY_SCOPE_AGENT);
            }
            asm volatile("s_waitcnt vmcnt(0)" ::: "memory");  // h acked at L3
            __syncthreads();
            if (tid == 0) bar_signal(flags, bid, (unsigned)(t + 1));
        }
    } else {
        // ===================== heater block =====================
        // Register-only FMA chains keep this CU (and the clock governor)
        // busy while workers run their latency chain. tid0 polls the done
        // condition (~every 1-2k cycles); all other lanes watch LDS.
        float a = 1.0001f, b = 0.9999f, c2 = 1.0002f, d = 0.9998f;
        for (;;) {
            #pragma unroll
            for (int i = 0; i < 256; i++) {
                a  = __builtin_fmaf(a,  0.99990f,  1.0e-4f);
                b  = __builtin_fmaf(b,  1.00010f, -1.0e-4f);
                c2 = __builtin_fmaf(c2, 0.99980f,  2.0e-4f);
                d  = __builtin_fmaf(d,  1.00020f, -2.0e-4f);
            }
            if (tid == 0) {
                unsigned f0 = __hip_atomic_load(&flags[0], __ATOMIC_RELAXED,
                                                __HIP_MEMORY_SCOPE_AGENT);
                if (f0 >= (unsigned)SEQ) hdone = 1u;
            }
            if (hdone) break;
        }
        asm volatile("" :: "v"(a), "v"(b), "v"(c2), "v"(d));  // keep chains live
    }

    cg::this_grid().sync();   // all blocks (workers + heaters) converge

    // ---- FC epilogue over the FULL grid: 131072 threads, 1 iter ----
    for (unsigned idx = (unsigned)bid * NTHR + tid; idx < BATCH * CLASSES;
         idx += (unsigned)GRID * NTHR) {
        const int b   = idx / CLASSES;
        const int cls = idx % CLASSES;
        const unsigned short* hrow = h0 + (size_t)b * HID;   // SEQ even
        const float* wrow = W_fc + (size_t)cls * HID;
        float acc = 0.f;
        #pragma unroll 4
        for (int k = 0; k < HID; k += 8) {
            bf16x8 hv = *(const bf16x8*)(hrow + k);
            float4 w0 = *(const float4*)(wrow + k);
            float4 w1 = *(const float4*)(wrow + k + 4);
            union { unsigned u; float f; } e;
            float s = 0.f;
            e.u = ((unsigned)(unsigned short)hv[0]) << 16; s += e.f * w0.x;
            e.u = ((unsigned)(unsigned short)hv[1]) << 16; s += e.f * w0.y;
            e.u = ((unsigned)(unsigned short)hv[2]) << 16; s += e.f * w0.z;
            e.u = ((unsigned)(unsigned short)hv[3]) << 16; s += e.f * w0.w;
            e.u = ((unsigned)(unsigned short)hv[4]) << 16; s += e.f * w1.x;
            e.u = ((unsigned)(unsigned short)hv[5]) << 16; s += e.f * w1.y;
            e.u = ((unsigned)(unsigned short)hv[6]) << 16; s += e.f * w1.z;
            e.u = ((unsigned)(unsigned short)hv[7]) << 16; s += e.f * w1.w;
            acc += s;
        }
        out[idx] = acc + b_fc[cls];
    }
}

extern "C" void kernel_launch(void* const* d_in, const int* in_sizes, int n_in,
                              void* d_out, int out_size, void* d_ws, size_t ws_size,
                              hipStream_t stream) {
    const float* x    = (const float*)d_in[0];
    const float* W_ih = (const float*)d_in[1];
    const float* W_hh = (const float*)d_in[2];
    const float* b_ih = (const float*)d_in[3];
    const float* b_hh = (const float*)d_in[4];
    const float* W_fc = (const float*)d_in[5];
    const float* b_fc = (const float*)d_in[6];
    float* out = (float*)d_out;

    // ws layout (R6-identical): h0 | h1 | xbf(64MB) | Wbf(4MB) | xpp(1GB fp32)
    const size_t OFF_H1   = (size_t)BATCH * HID * 2;
    const size_t OFF_XBF  = 2 * OFF_H1;
    const size_t XBF_B    = (size_t)SEQ * BATCH * INP * 2;
    const size_t OFF_WBF  = OFF_XBF + XBF_B;
    const size_t WBF_B    = (size_t)4 * HID * INP * 2;
    const size_t OFF_XPP  = OFF_WBF + WBF_B;
    const size_t XPP_B    = (size_t)SEQ * BATCH * G4H * 4;

    unsigned short* h0   = (unsigned short*)d_ws;
    unsigned short* h1   = (unsigned short*)((char*)d_ws + OFF_H1);
    unsigned short* xbf  = (unsigned short*)((char*)d_ws + OFF_XBF);
    unsigned short* Wbf  = (unsigned short*)((char*)d_ws + OFF_WBF);
    float*          xpp  = (float*)((char*)d_ws + OFF_XPP);

    int use_xbf = (ws_size >= OFF_XBF + XBF_B) ? 1 : 0;
    int use_xp  = (ws_size >= OFF_XPP + XPP_B) ? 1 : 0;

    if (use_xbf) {
        convert_bf16<<<dim3(2048), dim3(256), 0, stream>>>(x, W_ih, xbf, Wbf, use_xp);
    }
    if (use_xp) {
        xproj_gemm<<<dim3(512, 32), dim3(256), 0, stream>>>(xbf, Wbf, xpp);
    }

    unsigned* flags = (unsigned*)d_out;  // 128 words; overwritten by FC at end

    void* args[] = {&x, &W_ih, &W_hh, &b_ih, &b_hh, &W_fc, &b_fc, &out,
                    &h0, &h1, &xbf, &xpp, &use_xbf, &use_xp, &flags};
    hipLaunchCooperativeKernel((void*)lstm_fused, dim3(GRID), dim3(NTHR),
                               args, 0, stream);
}